// Round 6
// baseline (80.500 us; speedup 1.0000x reference)
//
#include <hip/hip_runtime.h>

#define BLK 256
#define NBLOCKS 3584   // 2048 (scale0) + 1024 (scale1) + 512 (scale2)

// Flat-grid scale decompose: block b ->
//   scale0: b in [0,2048)    n4=524288  sh=16  nb=2048
//   scale1: b in [2048,3072) n4=262144  sh=15  nb=1024
//   scale2: b in [3072,3584) n4=131072  sh=14  nb=512
//
// Anti-aliasing chunk swizzle: for memory item i, block lb processes chunk
// cb = (lb + 101*i) & (nb-1). The 10 concurrent M-streams of a wave then
// live in 10 DIFFERENT 4KB regions (distinct L2 set bits [17:7] and L3 set
// bits [23:7]) instead of differing only in bits >=23 (same set/bank ->
// serialized fills). Bijective per item => every chunk counted exactly once;
// per-chunk sums bitwise identical, only their partial-slot labels permute.

// ---------------------------------------------------------------------------
__global__ __launch_bounds__(BLK) void
dist_kernel(const float* __restrict__ f1, const float* __restrict__ M1,
            const float* __restrict__ f2, const float* __restrict__ M2,
            const float* __restrict__ f3, const float* __restrict__ M3,
            float* __restrict__ out, float* __restrict__ partials) {
    const int b = blockIdx.x;
    const float* f; const float* M; int n4, sh, lb, nbm1; float* CI;
    if (b < 2048)      { f = f1; M = M1; n4 = 524288; sh = 16; lb = b;        nbm1 = 2047; CI = out;           }
    else if (b < 3072) { f = f2; M = M2; n4 = 262144; sh = 15; lb = b - 2048; nbm1 = 1023; CI = out + 4194304; }
    else               { f = f3; M = M3; n4 = 131072; sh = 14; lb = b - 3072; nbm1 = 511;  CI = out + 6291456; }
    const int tid = lb * BLK + threadIdx.x;

    const float4* __restrict__ f4 = (const float4*)f;
    const float4* __restrict__ m4 = (const float4*)M;

    // f load (block's own chunk) + 10 M loads at per-item swizzled chunks.
    float4 a = f4[tid];
    float4 mv[10];
    #pragma unroll
    for (int i = 0; i < 10; ++i) {
        const int cb = (lb + 101 * i) & nbm1;          // bijective chunk shift
        mv[i] = m4[(size_t)i * n4 + cb * BLK + threadIdx.x];
    }

    // Feature -> CI first half (f already in registers).
    {
        const int bi = tid >> sh, r = tid & ((1 << sh) - 1);
        ((float4*)CI)[((size_t)bi << (sh + 1)) + r] = a;
    }

    // NOTE: distance for item i must pair f-chunk cb with M-chunk cb.
    // So the f value used for item i must come from chunk cb too!
    // => load the f float4 of each item's chunk as well. f chunks are hot in
    // L2 (each f chunk is read by ~10 blocks) so these extra 10 loads are
    // cheap L2 hits; unique-fabric traffic unchanged.
    float acc[10];
    #pragma unroll
    for (int i = 0; i < 10; ++i) {
        const int cb = (lb + 101 * i) & nbm1;
        float4 av = (cb == lb) ? a : f4[cb * BLK + threadIdx.x];
        float dx = av.x - mv[i].x, dy = av.y - mv[i].y;
        float dz = av.z - mv[i].z, dw = av.w - mv[i].w;
        acc[i] = dx * dx + dy * dy + dz * dz + dw * dw;
    }

    __shared__ float s[10][4];
    #pragma unroll
    for (int i = 0; i < 10; ++i) {
        float v = acc[i];
        #pragma unroll
        for (int off = 32; off > 0; off >>= 1) v += __shfl_down(v, off);
        if ((threadIdx.x & 63) == 0) s[i][threadIdx.x >> 6] = v;
    }
    __syncthreads();
    if (threadIdx.x < 10)
        partials[threadIdx.x * NBLOCKS + b] =
            s[threadIdx.x][0] + s[threadIdx.x][1] + s[threadIdx.x][2] + s[threadIdx.x][3];
}

// ---------------------------------------------------------------------------
// Reduce partials per (item, scale), then argmin over
// sqrt(s0)+sqrt(s1)+sqrt(s2). 1 block x 1024 threads; wave w (<10) owns
// item w and keeps the three scale ranges separate while summing.
// ---------------------------------------------------------------------------
__global__ void reduce_argmin_kernel(const float* __restrict__ partials,
                                     int* __restrict__ idx_out) {
    __shared__ float tot[10];
    const int wv = threadIdx.x >> 6, lane = threadIdx.x & 63;
    if (wv < 10) {
        const float* p = partials + wv * NBLOCKS;
        float s0 = 0.f, s1 = 0.f, s2 = 0.f;
        for (int i = lane; i < 2048; i += 64) s0 += p[i];
        for (int i = 2048 + lane; i < 3072; i += 64) s1 += p[i];
        for (int i = 3072 + lane; i < 3584; i += 64) s2 += p[i];
        #pragma unroll
        for (int off = 32; off > 0; off >>= 1) {
            s0 += __shfl_down(s0, off);
            s1 += __shfl_down(s1, off);
            s2 += __shfl_down(s2, off);
        }
        if (lane == 0) tot[wv] = sqrtf(s0) + sqrtf(s1) + sqrtf(s2);
    }
    __syncthreads();
    if (threadIdx.x == 0) {
        float best = 3.4e38f; int bi = 0;
        for (int i = 0; i < 10; ++i) {
            float t = tot[i];
            if (t < best) { best = t; bi = i; }
        }
        *idx_out = bi;
    }
}

// ---------------------------------------------------------------------------
// Gather: M[idx] float4 -> CI second half + mi. (Feature half already done.)
// ---------------------------------------------------------------------------
__global__ void gather_kernel(const float* __restrict__ M1, const float* __restrict__ M2,
                              const float* __restrict__ M3, const int* __restrict__ idx_ptr,
                              float* __restrict__ out) {
    const int b = blockIdx.x;
    const float* M; int n4, sh, lb; float* CI; float* mi;
    if (b < 2048)      { M = M1; n4 = 524288; sh = 16; lb = b;        CI = out;           mi = out + 7340032;  }
    else if (b < 3072) { M = M2; n4 = 262144; sh = 15; lb = b - 2048; CI = out + 4194304; mi = out + 9437184;  }
    else               { M = M3; n4 = 131072; sh = 14; lb = b - 3072; CI = out + 6291456; mi = out + 10485760; }
    const int tid = lb * BLK + threadIdx.x;
    const int idx = *idx_ptr;

    float4 v = ((const float4*)M)[(size_t)idx * n4 + tid];
    const int bi = tid >> sh, r = tid & ((1 << sh) - 1);
    const int S4 = 1 << sh;
    ((float4*)CI)[((size_t)bi << (sh + 1)) + S4 + r] = v;
    ((float4*)mi)[tid] = v;
}

extern "C" void kernel_launch(void* const* d_in, const int* in_sizes, int n_in,
                              void* d_out, int out_size, void* d_ws, size_t ws_size,
                              hipStream_t stream) {
    const float* f1 = (const float*)d_in[0];
    const float* f2 = (const float*)d_in[1];
    const float* f3 = (const float*)d_in[2];
    const float* M1 = (const float*)d_in[3];
    const float* M2 = (const float*)d_in[4];
    const float* M3 = (const float*)d_in[5];
    float* out = (float*)d_out;

    // Output flat layout (fp32 elements):
    //   CI1 @ 0         4194304 | CI2 @ 4194304  2097152 | CI3 @ 6291456  1048576
    //   mi1 @ 7340032   2097152 | mi2 @ 9437184  1048576 | mi3 @ 10485760  524288
    // Scratch: partials (10*NBLOCKS fp32 = 143 KB) in the mi3 region (fully
    // overwritten by gather afterwards). idx in d_ws.
    float* partials = out + 10485760;
    int* idxp = (int*)d_ws;

    dist_kernel<<<NBLOCKS, BLK, 0, stream>>>(f1, M1, f2, M2, f3, M3, out, partials);
    reduce_argmin_kernel<<<1, 1024, 0, stream>>>(partials, idxp);
    gather_kernel<<<NBLOCKS, BLK, 0, stream>>>(M1, M2, M3, idxp, out);
}

// Round 8
// 56.045 us; speedup vs baseline: 1.4364x; 1.4364x over previous
//
#include <hip/hip_runtime.h>

#define BLK 256
#define MAXB 512      // partial slots per (scale,item) pair
#define NB_G 3584     // gather flat grid: 2048 + 1024 + 512

// ---------------------------------------------------------------------------
// Distance kernel — R2's proven many-block shape, 2 items per block:
// grid (512, 15), py = scale*5 + ipair, items {2*ipair, 2*ipair+1}.
// 3 streams/block (f, M_even, M_odd): f logical re-reads drop 10x -> 5x.
// Each active block: 4 float4 per thread per stream, stride S = nblocks*BLK.
// Deterministic per-block partials (no atomics, no memset).
// ---------------------------------------------------------------------------
__global__ __launch_bounds__(BLK) void
dist_kernel(const float* __restrict__ f1, const float* __restrict__ M1,
            const float* __restrict__ f2, const float* __restrict__ M2,
            const float* __restrict__ f3, const float* __restrict__ M3,
            float* __restrict__ partials) {
    const int py    = blockIdx.y;
    const int scale = py >= 10 ? 2 : (py >= 5 ? 1 : 0);
    const int item0 = (py - scale * 5) * 2;
    const float* f; const float* M; int n4;
    if (scale == 0)      { f = f1; M = M1; n4 = 524288; }
    else if (scale == 1) { f = f2; M = M2; n4 = 262144; }
    else                 { f = f3; M = M3; n4 = 131072; }
    const int nblocks = n4 >> 10;          // n4 / (BLK*4)
    if ((int)blockIdx.x >= nblocks) return;

    const float4* __restrict__ f4  = (const float4*)f;
    const float4* __restrict__ m4a = (const float4*)M + (size_t)item0 * n4;
    const float4* __restrict__ m4b = m4a + n4;
    const int tid = blockIdx.x * BLK + threadIdx.x;
    const int S   = nblocks * BLK;

    float4 a0 = f4[tid];
    float4 b0 = m4a[tid];
    float4 c0 = m4b[tid];
    float4 a1 = f4[tid + S];
    float4 b1 = m4a[tid + S];
    float4 c1 = m4b[tid + S];
    float4 a2 = f4[tid + 2 * S];
    float4 b2 = m4a[tid + 2 * S];
    float4 c2 = m4b[tid + 2 * S];
    float4 a3 = f4[tid + 3 * S];
    float4 b3 = m4a[tid + 3 * S];
    float4 c3 = m4b[tid + 3 * S];

    float acc0 = 0.f, acc1 = 0.f;
    {
        float dx, dy, dz, dw;
        dx = a0.x - b0.x; dy = a0.y - b0.y; dz = a0.z - b0.z; dw = a0.w - b0.w;
        acc0 += dx * dx + dy * dy + dz * dz + dw * dw;
        dx = a1.x - b1.x; dy = a1.y - b1.y; dz = a1.z - b1.z; dw = a1.w - b1.w;
        acc0 += dx * dx + dy * dy + dz * dz + dw * dw;
        dx = a2.x - b2.x; dy = a2.y - b2.y; dz = a2.z - b2.z; dw = a2.w - b2.w;
        acc0 += dx * dx + dy * dy + dz * dz + dw * dw;
        dx = a3.x - b3.x; dy = a3.y - b3.y; dz = a3.z - b3.z; dw = a3.w - b3.w;
        acc0 += dx * dx + dy * dy + dz * dz + dw * dw;

        dx = a0.x - c0.x; dy = a0.y - c0.y; dz = a0.z - c0.z; dw = a0.w - c0.w;
        acc1 += dx * dx + dy * dy + dz * dz + dw * dw;
        dx = a1.x - c1.x; dy = a1.y - c1.y; dz = a1.z - c1.z; dw = a1.w - c1.w;
        acc1 += dx * dx + dy * dy + dz * dz + dw * dw;
        dx = a2.x - c2.x; dy = a2.y - c2.y; dz = a2.z - c2.z; dw = a2.w - c2.w;
        acc1 += dx * dx + dy * dy + dz * dz + dw * dw;
        dx = a3.x - c3.x; dy = a3.y - c3.y; dz = a3.z - c3.z; dw = a3.w - c3.w;
        acc1 += dx * dx + dy * dy + dz * dz + dw * dw;
    }

    #pragma unroll
    for (int off = 32; off > 0; off >>= 1) {
        acc0 += __shfl_down(acc0, off);
        acc1 += __shfl_down(acc1, off);
    }

    __shared__ float s[2][BLK / 64];
    if ((threadIdx.x & 63) == 0) {
        s[0][threadIdx.x >> 6] = acc0;
        s[1][threadIdx.x >> 6] = acc1;
    }
    __syncthreads();
    if (threadIdx.x == 0) {
        const int p0 = scale * 10 + item0;
        partials[p0 * MAXB + blockIdx.x]       = s[0][0] + s[0][1] + s[0][2] + s[0][3];
        partials[(p0 + 1) * MAXB + blockIdx.x] = s[1][0] + s[1][1] + s[1][2] + s[1][3];
    }
}

// ---------------------------------------------------------------------------
// Reduce partials per (scale,item) + argmin over sqrt(s0)+sqrt(s1)+sqrt(s2).
// 1 block x 256 threads; wave w handles pairs w, w+4, ...
// ---------------------------------------------------------------------------
__global__ void reduce_argmin_kernel(const float* __restrict__ partials,
                                     int* __restrict__ idx_out) {
    __shared__ float tot[30];
    const int wv = threadIdx.x >> 6, lane = threadIdx.x & 63;
    for (int p = wv; p < 30; p += 4) {
        const int scale = p >= 20 ? 2 : (p >= 10 ? 1 : 0);
        const int nb = MAXB >> scale;
        float s = 0.f;
        for (int i = lane; i < nb; i += 64) s += partials[p * MAXB + i];
        #pragma unroll
        for (int off = 32; off > 0; off >>= 1) s += __shfl_down(s, off);
        if (lane == 0) tot[p] = s;
    }
    __syncthreads();
    if (threadIdx.x == 0) {
        float best = 3.4e38f; int bi = 0;
        for (int i = 0; i < 10; ++i) {
            float t = sqrtf(tot[i]) + sqrtf(tot[10 + i]) + sqrtf(tot[20 + i]);
            if (t < best) { best = t; bi = i; }
        }
        *idx_out = bi;
    }
}

// ---------------------------------------------------------------------------
// Full gather (R1-proven: the FINAL node writes every output byte):
// feature -> CI first half; M[idx] -> CI second half + mi.
// Flat grid: scale0 [0,2048), scale1 [2048,3072), scale2 [3072,3584).
// ---------------------------------------------------------------------------
__global__ void gather_kernel(const float* __restrict__ f1, const float* __restrict__ M1,
                              const float* __restrict__ f2, const float* __restrict__ M2,
                              const float* __restrict__ f3, const float* __restrict__ M3,
                              const int* __restrict__ idx_ptr, float* __restrict__ out) {
    const int b = blockIdx.x;
    const float* f; const float* M; int n4, sh, lb; float* CI; float* mi;
    if (b < 2048)      { f = f1; M = M1; n4 = 524288; sh = 16; lb = b;        CI = out;           mi = out + 7340032;  }
    else if (b < 3072) { f = f2; M = M2; n4 = 262144; sh = 15; lb = b - 2048; CI = out + 4194304; mi = out + 9437184;  }
    else               { f = f3; M = M3; n4 = 131072; sh = 14; lb = b - 3072; CI = out + 6291456; mi = out + 10485760; }
    const int tid = lb * BLK + threadIdx.x;
    const int idx = *idx_ptr;

    float4 va = ((const float4*)f)[tid];
    float4 vb = ((const float4*)M)[(size_t)idx * n4 + tid];
    const int bi = tid >> sh, r = tid & ((1 << sh) - 1);
    const int S4 = 1 << sh;
    const size_t cbase = ((size_t)bi << (sh + 1)) + r;
    ((float4*)CI)[cbase]      = va;
    ((float4*)CI)[cbase + S4] = vb;
    ((float4*)mi)[tid]        = vb;
}

extern "C" void kernel_launch(void* const* d_in, const int* in_sizes, int n_in,
                              void* d_out, int out_size, void* d_ws, size_t ws_size,
                              hipStream_t stream) {
    const float* f1 = (const float*)d_in[0];
    const float* f2 = (const float*)d_in[1];
    const float* f3 = (const float*)d_in[2];
    const float* M1 = (const float*)d_in[3];
    const float* M2 = (const float*)d_in[4];
    const float* M3 = (const float*)d_in[5];
    float* out = (float*)d_out;

    // Output flat layout (fp32 elements):
    //   CI1 @ 0         4194304 | CI2 @ 4194304  2097152 | CI3 @ 6291456  1048576
    //   mi1 @ 7340032   2097152 | mi2 @ 9437184  1048576 | mi3 @ 10485760  524288
    // Scratch: partials (30*512 fp32 = 61 KB) in the mi3 region; written by
    // dist, read by reduce, then FULLY overwritten by gather (final node
    // rewrites every output byte — the R1-proven replay-safe protocol).
    // idx in d_ws. No memset needed (all read slots are written each call).
    float* partials = out + 10485760;
    int* idxp = (int*)d_ws;

    dist_kernel<<<dim3(MAXB, 15), BLK, 0, stream>>>(f1, M1, f2, M2, f3, M3, partials);
    reduce_argmin_kernel<<<1, BLK, 0, stream>>>(partials, idxp);
    gather_kernel<<<NB_G, BLK, 0, stream>>>(f1, M1, f2, M2, f3, M3, idxp, out);
}

// Round 9
// 54.858 us; speedup vs baseline: 1.4674x; 1.0216x over previous
//
#include <hip/hip_runtime.h>

#define BLK 256
#define MAXB 512      // partial slots per (scale,item) pair; grid.x
#define NB_G 3584     // gather flat grid: 2048 + 1024 + 512

// ---------------------------------------------------------------------------
// Distance kernel — exact R2 shape (measured 5.8 TB/s read throughput, the
// best of 6 structural variants): grid (512, 30), pair = scale*10 + item,
// 2 streams per block (f, M[item]), 4 float4 per thread per stream at
// stride S = nblocks*BLK. Deterministic per-block partials (no atomics).
// f re-reads (10x) are the price of the only shape that sustains full
// per-CU load throughput (3+ streams/block measured 29-55% slower).
// ---------------------------------------------------------------------------
__global__ __launch_bounds__(BLK) void
dist_kernel(const float* __restrict__ f1, const float* __restrict__ M1,
            const float* __restrict__ f2, const float* __restrict__ M2,
            const float* __restrict__ f3, const float* __restrict__ M3,
            float* __restrict__ partials) {
    const int pair  = blockIdx.y;
    const int scale = pair >= 20 ? 2 : (pair >= 10 ? 1 : 0);
    const int item  = pair - scale * 10;
    const float* f; const float* M; int n4;
    if (scale == 0)      { f = f1; M = M1; n4 = 524288; }
    else if (scale == 1) { f = f2; M = M2; n4 = 262144; }
    else                 { f = f3; M = M3; n4 = 131072; }
    const int nblocks = n4 >> 10;          // n4 / (BLK*4)
    if ((int)blockIdx.x >= nblocks) return;

    const float4* __restrict__ f4 = (const float4*)f;
    const float4* __restrict__ m4 = (const float4*)M + (size_t)item * n4;
    const int tid = blockIdx.x * BLK + threadIdx.x;
    const int S   = nblocks * BLK;

    float4 a0 = f4[tid];
    float4 b0 = m4[tid];
    float4 a1 = f4[tid + S];
    float4 b1 = m4[tid + S];
    float4 a2 = f4[tid + 2 * S];
    float4 b2 = m4[tid + 2 * S];
    float4 a3 = f4[tid + 3 * S];
    float4 b3 = m4[tid + 3 * S];

    float acc = 0.f;
    {
        float dx, dy, dz, dw;
        dx = a0.x - b0.x; dy = a0.y - b0.y; dz = a0.z - b0.z; dw = a0.w - b0.w;
        acc += dx * dx + dy * dy + dz * dz + dw * dw;
        dx = a1.x - b1.x; dy = a1.y - b1.y; dz = a1.z - b1.z; dw = a1.w - b1.w;
        acc += dx * dx + dy * dy + dz * dz + dw * dw;
        dx = a2.x - b2.x; dy = a2.y - b2.y; dz = a2.z - b2.z; dw = a2.w - b2.w;
        acc += dx * dx + dy * dy + dz * dz + dw * dw;
        dx = a3.x - b3.x; dy = a3.y - b3.y; dz = a3.z - b3.z; dw = a3.w - b3.w;
        acc += dx * dx + dy * dy + dz * dz + dw * dw;
    }

    #pragma unroll
    for (int off = 32; off > 0; off >>= 1) acc += __shfl_down(acc, off);

    __shared__ float s[BLK / 64];
    if ((threadIdx.x & 63) == 0) s[threadIdx.x >> 6] = acc;
    __syncthreads();
    if (threadIdx.x == 0)
        partials[pair * MAXB + blockIdx.x] = s[0] + s[1] + s[2] + s[3];
}

// ---------------------------------------------------------------------------
// Reduce partials per (scale,item) + argmin over sqrt(s0)+sqrt(s1)+sqrt(s2).
// 1 block x 256 threads; wave w handles pairs w, w+4, ...
// ---------------------------------------------------------------------------
__global__ void reduce_argmin_kernel(const float* __restrict__ partials,
                                     int* __restrict__ idx_out) {
    __shared__ float tot[30];
    const int wv = threadIdx.x >> 6, lane = threadIdx.x & 63;
    for (int p = wv; p < 30; p += 4) {
        const int scale = p >= 20 ? 2 : (p >= 10 ? 1 : 0);
        const int nb = MAXB >> scale;
        float s = 0.f;
        for (int i = lane; i < nb; i += 64) s += partials[p * MAXB + i];
        #pragma unroll
        for (int off = 32; off > 0; off >>= 1) s += __shfl_down(s, off);
        if (lane == 0) tot[p] = s;
    }
    __syncthreads();
    if (threadIdx.x == 0) {
        float best = 3.4e38f; int bi = 0;
        for (int i = 0; i < 10; ++i) {
            float t = sqrtf(tot[i]) + sqrtf(tot[10 + i]) + sqrtf(tot[20 + i]);
            if (t < best) { best = t; bi = i; }
        }
        *idx_out = bi;
    }
}

// ---------------------------------------------------------------------------
// Full gather (replay-safe protocol: the FINAL node writes every output
// byte): feature -> CI first half; M[idx] -> CI second half + mi.
// Flat grid: scale0 [0,2048), scale1 [2048,3072), scale2 [3072,3584).
// ---------------------------------------------------------------------------
__global__ void gather_kernel(const float* __restrict__ f1, const float* __restrict__ M1,
                              const float* __restrict__ f2, const float* __restrict__ M2,
                              const float* __restrict__ f3, const float* __restrict__ M3,
                              const int* __restrict__ idx_ptr, float* __restrict__ out) {
    const int b = blockIdx.x;
    const float* f; const float* M; int n4, sh, lb; float* CI; float* mi;
    if (b < 2048)      { f = f1; M = M1; n4 = 524288; sh = 16; lb = b;        CI = out;           mi = out + 7340032;  }
    else if (b < 3072) { f = f2; M = M2; n4 = 262144; sh = 15; lb = b - 2048; CI = out + 4194304; mi = out + 9437184;  }
    else               { f = f3; M = M3; n4 = 131072; sh = 14; lb = b - 3072; CI = out + 6291456; mi = out + 10485760; }
    const int tid = lb * BLK + threadIdx.x;
    const int idx = *idx_ptr;

    float4 va = ((const float4*)f)[tid];
    float4 vb = ((const float4*)M)[(size_t)idx * n4 + tid];
    const int bi = tid >> sh, r = tid & ((1 << sh) - 1);
    const int S4 = 1 << sh;
    const size_t cbase = ((size_t)bi << (sh + 1)) + r;
    ((float4*)CI)[cbase]      = va;
    ((float4*)CI)[cbase + S4] = vb;
    ((float4*)mi)[tid]        = vb;
}

extern "C" void kernel_launch(void* const* d_in, const int* in_sizes, int n_in,
                              void* d_out, int out_size, void* d_ws, size_t ws_size,
                              hipStream_t stream) {
    const float* f1 = (const float*)d_in[0];
    const float* f2 = (const float*)d_in[1];
    const float* f3 = (const float*)d_in[2];
    const float* M1 = (const float*)d_in[3];
    const float* M2 = (const float*)d_in[4];
    const float* M3 = (const float*)d_in[5];
    float* out = (float*)d_out;

    // Output flat layout (fp32 elements):
    //   CI1 @ 0         4194304 | CI2 @ 4194304  2097152 | CI3 @ 6291456  1048576
    //   mi1 @ 7340032   2097152 | mi2 @ 9437184  1048576 | mi3 @ 10485760  524288
    // Scratch: partials (30*512 fp32 = 61 KB) in the mi3 region; written by
    // dist, read by reduce, then FULLY overwritten by gather (final node
    // rewrites every output byte — the replay-safe protocol proven in
    // R1/R8; fusing output writes into dist failed post-timing in R7).
    // idx in d_ws. No memset needed (all read slots written every call).
    float* partials = out + 10485760;
    int* idxp = (int*)d_ws;

    dist_kernel<<<dim3(MAXB, 30), BLK, 0, stream>>>(f1, M1, f2, M2, f3, M3, partials);
    reduce_argmin_kernel<<<1, BLK, 0, stream>>>(partials, idxp);
    gather_kernel<<<NB_G, BLK, 0, stream>>>(f1, M1, f2, M2, f3, M3, idxp, out);
}